// Round 10
// baseline (512.603 us; speedup 1.0000x reference)
//
#include <hip/hip_runtime.h>
#include <math.h>

// ---------------------------------------------------------------------------
// ActorNetwork forward, MI355X (gfx950). Round 10: code-size shrink.
// R6 falsified MLP theory (30x in-flight -> same 163us). R9 falsified the
// barrier theory (20->4 barriers -> only 163->158us; MfmaUtil/VALUBusy
// unchanged at 5%/20%). Remaining candidate fitting ALL observations (issue
// starvation on every pipe, invariant to data-path restructure): I$ thrash --
// fully-unrolled text ~25-32KB vs 32KB L1 I-cache, 3 co-resident blocks at
// different phases. This round: SAME math/indices/barriers as verified R9,
// but every heavy phase is a "#pragma unroll 1" rolled loop (no runtime-
// indexed register arrays: frags re-read from LDS/L2 inside loops; softmax
// al[] replaced by on-the-fly shfl+exp recompute in identical order).
// Target text ~6-10KB. Shapes: B=65536,N=8,OBS0=6,OBS1=1024,OBS2=7,H=64,
// HC=128,NA=2.
// ---------------------------------------------------------------------------

typedef float f32x4 __attribute__((ext_vector_type(4)));
typedef float f32x4u __attribute__((ext_vector_type(4), aligned(4)));
typedef float f32x2u __attribute__((ext_vector_type(2), aligned(4)));
typedef __bf16 bf16x8 __attribute__((ext_vector_type(8)));
typedef unsigned short u16x8 __attribute__((ext_vector_type(8)));

#define DI __device__ __forceinline__

DI unsigned short f2bf_u(float f) {  // fp32 -> bf16 bits, RTNE
  unsigned u = __builtin_bit_cast(unsigned, f);
  u += 0x7fffu + ((u >> 16) & 1u);
  return (unsigned short)(u >> 16);
}
DI float bfu2f(unsigned short s) {
  unsigned u = ((unsigned)s) << 16;
  return __builtin_bit_cast(float, u);
}
DI u16x8 cvt8(f32x4 x, f32x4 y) {
  bf16x8 r;
  r[0] = (__bf16)x[0]; r[1] = (__bf16)x[1]; r[2] = (__bf16)x[2]; r[3] = (__bf16)x[3];
  r[4] = (__bf16)y[0]; r[5] = (__bf16)y[1]; r[6] = (__bf16)y[2]; r[7] = (__bf16)y[3];
  return __builtin_bit_cast(u16x8, r);
}
DI f32x4 mfma16(u16x8 a, u16x8 b, f32x4 c) {
  return __builtin_amdgcn_mfma_f32_16x16x32_bf16(
      __builtin_bit_cast(bf16x8, a), __builtin_bit_cast(bf16x8, b), c, 0, 0, 0);
}
DI void gload_lds16(const void* g, void* l) {  // async global->LDS, 16 B/lane
  typedef __attribute__((address_space(1))) const unsigned GU;
  typedef __attribute__((address_space(3))) unsigned LU;
  __builtin_amdgcn_global_load_lds((GU*)g, (LU*)l, 16, 0, 0);
}

// Fragment layouts (learn_hip m89/m91):
//   A-frag: lane l holds A[m = l&15][k = (l>>4)*8 + j], j=0..7
//   B-frag: lane l holds B[k = (l>>4)*8 + j][n = l&15]
//   C/D   : lane l holds C[row = (l>>4)*4 + ri][col = l&15]

// ---- workspace layout (bytes) ----
constexpr size_t WS_WGF = 0;        // Wg frags  [32kt][4nt]   131072
constexpr size_t WS_WS2 = 131072;   // Ws2 frags [2][4]          8192
constexpr size_t WS_WV  = 139264;   // Wv frags  [2][4]          8192
constexpr size_t WS_MQK = 147456;   // Mqk frags [2][4]          8192
constexpr size_t WS_WC1 = 155648;   // Wc1 frags [6][8]         49152
constexpr size_t WS_WC2 = 204800;   // Wc2 frags [4][8]         32768

// ---------------------------------------------------------------------------
// k_prep: pack all weights into bf16 B-frag layout; M_qk computed inline.
// ---------------------------------------------------------------------------
__global__ __launch_bounds__(256) void k_prep(
    const float* __restrict__ Wg, const float* __restrict__ Ws2,
    const float* __restrict__ Wv, const float* __restrict__ Wq,
    const float* __restrict__ Wk, const float* __restrict__ Wc1,
    const float* __restrict__ Wc2,
    unsigned short* __restrict__ wgf, unsigned short* __restrict__ ws2f,
    unsigned short* __restrict__ wvf, unsigned short* __restrict__ mqkf,
    unsigned short* __restrict__ wc1f, unsigned short* __restrict__ wc2f) {
  const int idx = blockIdx.x * 256 + threadIdx.x;  // 118784 total
  const float* src = nullptr;
  unsigned short* dst;
  int i, ntm, NC;
  bool is_mqk = false;
  if (idx < 65536)      { src = Wg;  dst = wgf;  i = idx;          ntm = 2; NC = 64;  }
  else if (idx < 69632) { src = Ws2; dst = ws2f; i = idx - 65536;  ntm = 2; NC = 64;  }
  else if (idx < 73728) { src = Wv;  dst = wvf;  i = idx - 69632;  ntm = 2; NC = 64;  }
  else if (idx < 77824) { is_mqk = true; dst = mqkf; i = idx - 73728; ntm = 2; NC = 64; }
  else if (idx < 102400){ src = Wc1; dst = wc1f; i = idx - 77824;  ntm = 3; NC = 128; }
  else                  { src = Wc2; dst = wc2f; i = idx - 102400; ntm = 3; NC = 128; }
  const int j = i & 7, ln = (i >> 3) & 63, t2 = i >> 9;
  const int nt = t2 & ((1 << ntm) - 1), kt = t2 >> ntm;
  const int k = kt * 32 + (ln >> 4) * 8 + j, n = nt * 16 + (ln & 15);
  float val;
  if (is_mqk) {  // M_qk[k][n] = dot(Wq[k,:], Wk[n,:])
    const f32x4* qp = (const f32x4*)(Wq + k * 64);
    const f32x4* kp = (const f32x4*)(Wk + n * 64);
    float acc = 0.f;
#pragma unroll 1
    for (int d4 = 0; d4 < 16; ++d4) {
      const f32x4 a = qp[d4], b = kp[d4];
#pragma unroll
      for (int e = 0; e < 4; ++e) acc = fmaf(a[e], b[e], acc);
    }
    val = acc;
  } else {
    val = src[k * NC + n];
  }
  dst[i] = f2bf_u(val);
}

// ---------------------------------------------------------------------------
// k_main: 32 batch rows / block, 2048 blocks x 256 thr, 4 barriers, rolled.
// ---------------------------------------------------------------------------
__global__ __launch_bounds__(256, 3) void k_main(
    const float* __restrict__ s0, const float* __restrict__ s1,
    const float* __restrict__ s2,
    const float* __restrict__ W0, const float* __restrict__ b0v,
    const unsigned short* __restrict__ wgf, const float* __restrict__ bg,
    const float* __restrict__ Ws1, const float* __restrict__ bs1,
    const unsigned short* __restrict__ ws2f, const float* __restrict__ bs2,
    const unsigned short* __restrict__ wvf, const unsigned short* __restrict__ mqkf,
    const unsigned short* __restrict__ wc1f, const float* __restrict__ bc1,
    const unsigned short* __restrict__ wc2f, const float* __restrict__ bc2,
    const float* __restrict__ Wc3, const float* __restrict__ bc3,
    float* __restrict__ out) {
  // LDS map (53760 B -> 3 blocks/CU): identical to R9 (verified).
  __shared__ __align__(16) char smem[53760];
  u16x8* EF = (u16x8*)smem;
  unsigned short* EFs = (unsigned short*)smem;
  u16x8* H1F = (u16x8*)smem;
  unsigned short* H1Fs = (unsigned short*)smem;
  float* H2 = (float*)(smem + 8192);
  u16x8* CF = (u16x8*)(smem + 32768);
  unsigned short* CFs = (unsigned short*)(smem + 32768);
  float* QKf = (float*)(smem + 40960);
  f32x4* RED = (f32x4*)(smem + 40960);
  u16x8* SEF = (u16x8*)(smem + 49664);

  const int tid = threadIdx.x;
  const int lane = tid & 63, wave = tid >> 6;
  const int lo = lane & 15, q = lane >> 4;
  const int bbase = blockIdx.x * 32;
  const int bl8 = tid >> 3, n8 = tid & 7;
  const int mt_q = wave >> 1;

  // ---- early global loads for phase A (held across env) ----
  const float* s2p = s2 + ((size_t)(bbase + bl8) * 8 + n8) * 7;
  const f32x4u x03 = *(const f32x4u*)s2p;
  const f32x2u x45 = *(const f32x2u*)(s2p + 4);
  const float x6 = s2p[6];

  // ---- env GEMM: per-wave staged, split-K; wave w: mt=w&1, K-half=w>>1 ----
  {
    const int mt_e = wave & 1, kh = wave >> 1;
    char* sbuf = smem + wave * 8192;  // wave-private; serial reuse of EF bytes
    const char* s1b = (const char*)s1 + (size_t)(bbase + mt_e * 16) * 4096 + kh * 2048;
    const u16x8* wg8 = (const u16x8*)wgf;
    f32x4 acc0 = {}, acc1 = {}, acc2 = {}, acc3 = {};
    const int sw = (lo & 7) << 4;
#pragma unroll 1
    for (int c = 0; c < 4; ++c) {  // 4 chunks of 128 cols (16 rows x 512 B)
      if (c) asm volatile("s_waitcnt lgkmcnt(0)" ::: "memory");
#pragma unroll 1
      for (int i = 0; i < 8; ++i) {  // LDS dest linear; source pre-swizzled
        const int T = (i * 64 + lane) * 16;
        const int rw = T >> 9, cb = T & 511;
        gload_lds16(s1b + (size_t)rw * 4096 + c * 512 + (cb ^ ((rw & 7) << 4)),
                    sbuf + T);
      }
      asm volatile("s_waitcnt vmcnt(0)" ::: "memory");  // per-wave wait
#pragma unroll 1
      for (int kt = 0; kt < 4; ++kt) {
        const int base = lo * 512 + kt * 128 + q * 32;
        const f32x4 alo = *(const f32x4*)(sbuf + (base ^ sw));
        const f32x4 ahi = *(const f32x4*)(sbuf + ((base + 16) ^ sw));
        const int ktg = kh * 16 + c * 4 + kt;
        const u16x8 af = cvt8(alo, ahi);
        acc0 = mfma16(af, wg8[(ktg * 4 + 0) * 64 + lane], acc0);
        acc1 = mfma16(af, wg8[(ktg * 4 + 1) * 64 + lane], acc1);
        acc2 = mfma16(af, wg8[(ktg * 4 + 2) * 64 + lane], acc2);
        acc3 = mfma16(af, wg8[(ktg * 4 + 3) * 64 + lane], acc3);
      }
    }
    if (kh == 1) {  // high-half partials -> RED
      RED[(mt_e * 4 + 0) * 64 + lane] = acc0;
      RED[(mt_e * 4 + 1) * 64 + lane] = acc1;
      RED[(mt_e * 4 + 2) * 64 + lane] = acc2;
      RED[(mt_e * 4 + 3) * 64 + lane] = acc3;
    }
    __syncthreads();  // B0 (only cross-wave point of env)
    if (kh == 0) {
      const f32x4 av[4] = {acc0, acc1, acc2, acc3};
#pragma unroll 1
      for (int nt = 0; nt < 4; ++nt) {
        const f32x4 a = av[nt] + RED[(mt_e * 4 + nt) * 64 + lane];
        const int h = nt * 16 + lo;
        const float bias = bg[h];
#pragma unroll
        for (int ri = 0; ri < 4; ++ri) {
          const float v = fmaxf(a[ri] + bias, 0.f);
          CFs[((mt_e * 4 + (h >> 5)) * 64 +
               ((((h >> 3) & 3) << 4) | (q * 4 + ri))) * 8 + (h & 7)] = f2bf_u(v);
        }
      }
    }
  }

  // ---- Phase A: E1 = relu(state2 @ Ws1 + bs1) -> EF (wave-local) ----
  bool maskreg;
  {
    float xv[7] = {x03[0], x03[1], x03[2], x03[3], x45[0], x45[1], x6};
    const float sum = xv[0] + xv[1] + xv[2] + xv[3] + xv[4] + xv[5] + xv[6];
    maskreg = (sum != 0.f);  // padded slots are exact zeros
    const int mt = tid >> 4, rl = tid & 15;
#pragma unroll 1
    for (int c = 0; c < 8; ++c) {
      float a[8];
#pragma unroll
      for (int i = 0; i < 8; ++i) a[i] = bs1[c * 8 + i];
#pragma unroll 1
      for (int j = 0; j < 7; ++j) {
        const float* wr = Ws1 + j * 64 + c * 8;
#pragma unroll
        for (int i = 0; i < 8; ++i) a[i] = fmaf(xv[j], wr[i], a[i]);
      }
      u16x8 pk;
#pragma unroll
      for (int i = 0; i < 8; ++i) pk[i] = f2bf_u(fmaxf(a[i], 0.f));
      EF[(mt * 2 + (c >> 2)) * 64 + (((c & 3) << 4) | rl)] = pk;
    }
  }
  // no barrier: wave-local

  // ---- Phase B: E2 = relu(E1 @ Ws2 + bs2), wave-local in-place ----
  {
    const u16x8* w2 = (const u16x8*)ws2f;
    u16x8 Bf00 = w2[(0 * 4 + 0) * 64 + lane], Bf01 = w2[(1 * 4 + 0) * 64 + lane];
    u16x8 Bf10 = w2[(0 * 4 + 1) * 64 + lane], Bf11 = w2[(1 * 4 + 1) * 64 + lane];
    u16x8 Bf20 = w2[(0 * 4 + 2) * 64 + lane], Bf21 = w2[(1 * 4 + 2) * 64 + lane];
    u16x8 Bf30 = w2[(0 * 4 + 3) * 64 + lane], Bf31 = w2[(1 * 4 + 3) * 64 + lane];
#pragma unroll 1
    for (int mi = 0; mi < 4; ++mi) {
      const int mt = wave * 4 + mi;
      const u16x8 A0 = EF[(mt * 2 + 0) * 64 + lane];
      const u16x8 A1 = EF[(mt * 2 + 1) * 64 + lane];
      f32x4 acc[4] = {};
      acc[0] = mfma16(A0, Bf00, acc[0]); acc[0] = mfma16(A1, Bf01, acc[0]);
      acc[1] = mfma16(A0, Bf10, acc[1]); acc[1] = mfma16(A1, Bf11, acc[1]);
      acc[2] = mfma16(A0, Bf20, acc[2]); acc[2] = mfma16(A1, Bf21, acc[2]);
      acc[3] = mfma16(A0, Bf30, acc[3]); acc[3] = mfma16(A1, Bf31, acc[3]);
#pragma unroll 1
      for (int nt = 0; nt < 4; ++nt) {
        const int h = nt * 16 + lo;
        const float bias = bs2[h];
        const f32x4 av = acc[nt];
#pragma unroll
        for (int ri = 0; ri < 4; ++ri) {
          const float v = fmaxf(av[ri] + bias, 0.f);
          const int rr = mt * 16 + q * 4 + ri;
          EFs[((mt * 2 + (h >> 5)) * 64 + ((((h >> 3) & 3) << 4) | (rr & 15))) * 8 +
              (h & 7)] = f2bf_u(v);
        }
      }
    }
  }
  // no barrier: wave-local

  // ---- C1: own_e redundant per wave, DIRECTLY in A-frag registers ----
  u16x8 cf0, cf1;
  {
    const float* s0r = s0 + (size_t)(bbase + mt_q * 16 + lo) * 6;
    float yv[6];
#pragma unroll
    for (int j = 0; j < 6; ++j) yv[j] = s0r[j];
#pragma unroll 1
    for (int half = 0; half < 2; ++half) {
      const int cb = half * 32 + q * 8;
      float a[8];
#pragma unroll
      for (int i = 0; i < 8; ++i) a[i] = b0v[cb + i];
#pragma unroll 1
      for (int j = 0; j < 6; ++j) {
        const float* wr = W0 + j * 64 + cb;
#pragma unroll
        for (int i = 0; i < 8; ++i) a[i] = fmaf(yv[j], wr[i], a[i]);
      }
      u16x8 pk;
#pragma unroll
      for (int i = 0; i < 8; ++i) pk[i] = f2bf_u(fmaxf(a[i], 0.f));
      if (half) cf1 = pk; else cf0 = pk;
    }
  }

  // ---- C2: qk = own_e @ M_qk, redundant per wave -> QK (dup-identical) ----
  {
    const u16x8* mq8 = (const u16x8*)mqkf;
#pragma unroll 1
    for (int nt = 0; nt < 4; ++nt) {
      f32x4 acc = {};
      acc = mfma16(cf0, mq8[(0 * 4 + nt) * 64 + lane], acc);
      acc = mfma16(cf1, mq8[(1 * 4 + nt) * 64 + lane], acc);
#pragma unroll
      for (int ri = 0; ri < 4; ++ri)
        QKf[(mt_q * 16 + q * 4 + ri) * 68 + nt * 16 + lo] = acc[ri];
    }
  }
  // no barrier: wave reads back only rows it wrote (sibling dup benign)

  // ---- C3: score = (E2_r . qk_b)/8, masked -> register ----
  float score;
  {
    const int mt = tid >> 4, rl = tid & 15;
    float dot = 0.f;
#pragma unroll 1
    for (int c = 0; c < 8; ++c) {
      const u16x8 e = EF[(mt * 2 + (c >> 2)) * 64 + (((c & 3) << 4) | rl)];
      const float* qkp = QKf + bl8 * 68 + c * 8;
      const f32x4 qa = *(const f32x4*)(qkp);
      const f32x4 qb = *(const f32x4*)(qkp + 4);
#pragma unroll
      for (int i = 0; i < 4; ++i) dot = fmaf(bfu2f(e[i]), qa[i], dot);
#pragma unroll
      for (int i = 0; i < 4; ++i) dot = fmaf(bfu2f(e[4 + i]), qb[i], dot);
    }
    score = maskreg ? dot * 0.125f : -1e30f;  // 1/sqrt(64)
  }

  // ---- C4: softmax stats in registers (shfl; sequential order preserved) ----
  float mxv, inv;
  {
    const int gb = lane & 56;
    mxv = __shfl(score, gb, 64);
#pragma unroll 1
    for (int n = 1; n < 8; ++n) mxv = fmaxf(mxv, __shfl(score, gb + n, 64));
    float sum = 0.f;
#pragma unroll 1
    for (int n = 0; n < 8; ++n) sum += __expf(__shfl(score, gb + n, 64) - mxv);
    inv = 1.f / sum;
  }

  // ---- C5: sE2_b = sum_n alpha_n * E2_{b,n} -> SEF (alpha recomputed
  //      on the fly: same exp inputs -> bit-identical to R9's al[n]) ----
  {
    const int gb = lane & 56;
    float a[8] = {0.f, 0.f, 0.f, 0.f, 0.f, 0.f, 0.f, 0.f};
#pragma unroll 1
    for (int n = 0; n < 8; ++n) {
      const float aln = __expf(__shfl(score, gb + n, 64) - mxv) * inv;
      const int rr = bl8 * 8 + n;
      const u16x8 e =
          EF[((rr >> 4) * 2 + (n8 >> 2)) * 64 + (((n8 & 3) << 4) | (rr & 15))];
#pragma unroll
      for (int i = 0; i < 8; ++i) a[i] = fmaf(aln, bfu2f(e[i]), a[i]);
    }
    u16x8 pk;
#pragma unroll
    for (int i = 0; i < 8; ++i) pk[i] = f2bf_u(a[i]);
    SEF[((bl8 >> 4) * 2 + (n8 >> 2)) * 64 + (((n8 & 3) << 4) | (bl8 & 15))] = pk;
  }
  __syncthreads();  // B1: SEF frag rows span both waves of an mt pair

  // ---- C6: v_att = sE2 @ Wv, redundant per wave -> CF kt 2,3 ----
  {
    const u16x8* wv8 = (const u16x8*)wvf;
    const u16x8 A0 = SEF[(mt_q * 2 + 0) * 64 + lane];
    const u16x8 A1 = SEF[(mt_q * 2 + 1) * 64 + lane];
#pragma unroll 1
    for (int nt = 0; nt < 4; ++nt) {
      f32x4 acc = {};
      acc = mfma16(A0, wv8[(0 * 4 + nt) * 64 + lane], acc);
      acc = mfma16(A1, wv8[(1 * 4 + nt) * 64 + lane], acc);
      const int h = nt * 16 + lo;
#pragma unroll
      for (int ri = 0; ri < 4; ++ri)
        CFs[((mt_q * 4 + 2 + (h >> 5)) * 64 +
             ((((h >> 3) & 3) << 4) | (q * 4 + ri))) * 8 + (h & 7)] =
            f2bf_u(acc[ri]);
    }
  }
  // no barrier: D1 reads this wave's own writes (sibling dup identical)

  // ---- D1: h1 = relu(concat @ Wc1 + bc1), K=192 (own=regs, env/vatt=CF) ----
  {
    const int ntb = (wave & 1) * 4;
    const u16x8* w18 = (const u16x8*)wc1f;
#pragma unroll 1
    for (int ni = 0; ni < 4; ++ni) {
      const int nt = ntb + ni;
      f32x4 acc = {};
      acc = mfma16(cf0, w18[(0 * 8 + nt) * 64 + lane], acc);
      acc = mfma16(cf1, w18[(1 * 8 + nt) * 64 + lane], acc);
#pragma unroll 1
      for (int kt = 0; kt < 4; ++kt) {  // frag re-read from LDS (no reg array)
        const u16x8 Af = CF[(mt_q * 4 + kt) * 64 + lane];
        acc = mfma16(Af, w18[((2 + kt) * 8 + nt) * 64 + lane], acc);
      }
      const float bias = bc1[nt * 16 + lo];
      const int h = nt * 16 + lo;
#pragma unroll
      for (int ri = 0; ri < 4; ++ri) {
        const float v = fmaxf(acc[ri] + bias, 0.f);
        const int rr = mt_q * 16 + q * 4 + ri;
        H1Fs[((mt_q * 4 + (h >> 5)) * 64 + ((((h >> 3) & 3) << 4) | (rr & 15))) * 8 +
             (h & 7)] = f2bf_u(v);
      }
    }
  }
  __syncthreads();  // B2: H1F kt slots written by both ntb waves of an mt

  // ---- D2: h2 = relu(h1 @ Wc2 + bc2) -> H2 fp32 [32][132] ----
  {
    const int ntb = (wave & 1) * 4;
    const u16x8* w28 = (const u16x8*)wc2f;
#pragma unroll 1
    for (int ni = 0; ni < 4; ++ni) {
      const int nt = ntb + ni;
      f32x4 acc = {};
#pragma unroll 1
      for (int kt = 0; kt < 4; ++kt) {
        const u16x8 Af = H1F[(mt_q * 4 + kt) * 64 + lane];
        acc = mfma16(Af, w28[(kt * 8 + nt) * 64 + lane], acc);
      }
      const float bias = bc2[nt * 16 + lo];
#pragma unroll
      for (int ri = 0; ri < 4; ++ri)
        H2[(mt_q * 16 + q * 4 + ri) * 132 + nt * 16 + lo] =
            fmaxf(acc[ri] + bias, 0.f);
    }
  }
  __syncthreads();  // B3: H2 rows read across waves in D3

  // ---- D3: out = tanh(h2 @ Wc3 + bc3) ----
  {
    const int kq = n8 >> 1, a = n8 & 1;
    const f32x4* h4 = (const f32x4*)(H2 + bl8 * 132 + kq * 32);
    const float* wr = Wc3 + kq * 64;
    float acc = 0.f;
#pragma unroll 1
    for (int j4 = 0; j4 < 8; ++j4) {
      const f32x4 hv = h4[j4];
#pragma unroll
      for (int e = 0; e < 4; ++e) acc = fmaf(hv[e], wr[(j4 * 4 + e) * 2 + a], acc);
    }
    acc += __shfl_down(acc, 2);
    acc += __shfl_down(acc, 4);
    if (kq == 0) out[(size_t)(bbase + bl8) * 2 + a] = tanhf(acc + bc3[a]);
  }
}

// ---------------------------------------------------------------------------
extern "C" void kernel_launch(void* const* d_in, const int* in_sizes, int n_in,
                              void* d_out, int out_size, void* d_ws, size_t ws_size,
                              hipStream_t stream) {
  const float* s0  = (const float*)d_in[0];
  const float* s1  = (const float*)d_in[1];
  const float* s2  = (const float*)d_in[2];
  const float* W0  = (const float*)d_in[3];
  const float* b0  = (const float*)d_in[4];
  const float* Wg  = (const float*)d_in[5];
  const float* bg  = (const float*)d_in[6];
  const float* Ws1 = (const float*)d_in[7];
  const float* bs1 = (const float*)d_in[8];
  const float* Ws2 = (const float*)d_in[9];
  const float* bs2 = (const float*)d_in[10];
  const float* Wq  = (const float*)d_in[11];
  const float* Wk  = (const float*)d_in[12];
  const float* Wv  = (const float*)d_in[13];
  const float* Wc1 = (const float*)d_in[14];
  const float* bc1 = (const float*)d_in[15];
  const float* Wc2 = (const float*)d_in[16];
  const float* bc2 = (const float*)d_in[17];
  const float* Wc3 = (const float*)d_in[18];
  const float* bc3 = (const float*)d_in[19];

  char* ws = (char*)d_ws;
  unsigned short* wgf  = (unsigned short*)(ws + WS_WGF);
  unsigned short* ws2f = (unsigned short*)(ws + WS_WS2);
  unsigned short* wvf  = (unsigned short*)(ws + WS_WV);
  unsigned short* mqkf = (unsigned short*)(ws + WS_MQK);
  unsigned short* wc1f = (unsigned short*)(ws + WS_WC1);
  unsigned short* wc2f = (unsigned short*)(ws + WS_WC2);

  hipLaunchKernelGGL(k_prep, dim3(464), dim3(256), 0, stream, Wg, Ws2, Wv, Wq,
                     Wk, Wc1, Wc2, wgf, ws2f, wvf, mqkf, wc1f, wc2f);
  hipLaunchKernelGGL(k_main, dim3(2048), dim3(256), 0, stream, s0, s1, s2, W0,
                     b0, wgf, bg, Ws1, bs1, ws2f, bs2, wvf, mqkf, wc1f, bc1,
                     wc2f, bc2, Wc3, bc3, (float*)d_out);
}